// Round 3
// baseline (345.064 us; speedup 1.0000x reference)
//
#include <hip/hip_runtime.h>
#include <math.h>

#define NREL 2
#define NB 10
#define C_OUT 40
#define CAP 64  // per-(node,rel) edge-list capacity; degrees ~Poisson(16), P(>64)~1e-19

typedef unsigned int u32;
typedef unsigned short u16;
typedef __attribute__((ext_vector_type(8))) short bf16x8;
typedef __attribute__((ext_vector_type(4))) float f32x4;

#define MFMA16 __builtin_amdgcn_mfma_f32_16x16x32_bf16

// split-bf16: v ~= bf16(v) + bf16(v - bf16(v)); returns (hi16<<16)|lo16
__device__ __forceinline__ u32 pack_split(float v) {
    u32 u = __float_as_uint(v);
    u32 hi = (u + 0x7FFFu + ((u >> 16) & 1u)) & 0xFFFF0000u;  // RNE to bf16
    float r = v - __uint_as_float(hi);
    u32 ur = __float_as_uint(r);
    u32 lo = ((ur + 0x7FFFu + ((ur >> 16) & 1u)) >> 16) & 0xFFFFu;
    return hi | lo;
}
__device__ __forceinline__ float bfbits(u32 w) { return __uint_as_float(w); }

// ---------------------------------------------------------------------------
// CSR build: capacity-64 bump allocation (no scan)
// ---------------------------------------------------------------------------
__global__ void zero_i32(int* __restrict__ p, int n) {
    int i = blockIdx.x * 256 + threadIdx.x;
    if (i < n) p[i] = 0;
}

__global__ void fill_edges_cap(const int* __restrict__ ei, const int* __restrict__ et,
                               int* __restrict__ cnt, int* __restrict__ elist, int E_) {
    int e = blockIdx.x * 256 + threadIdx.x;
    if (e < E_) {
        int src = ei[e];
        int dst = ei[E_ + e];
        int r = et[e];
        int idx = dst * 2 + r;
        int pos = atomicAdd(&cnt[idx], 1);
        if (pos < CAP) elist[idx * CAP + pos] = src;
    }
}

// ---------------------------------------------------------------------------
// Weight build (coalesced): Wt row c = [hi(768) | lo(768)] u16, k: root|W0|W1
// lanes = consecutive c -> basis/root reads coalesced. Thread does 4 ks.
// ---------------------------------------------------------------------------
__global__ void build_wt_coal(const float* __restrict__ basis, const float* __restrict__ comp,
                              const float* __restrict__ root, u16* __restrict__ Wt,
                              int dout_real) {
    int c = threadIdx.x;          // block = dout_pad threads
    int k0 = blockIdx.x * 4;      // grid = 192
    float cw[NREL][NB];
#pragma unroll
    for (int r = 0; r < NREL; ++r)
#pragma unroll
        for (int b = 0; b < NB; ++b) cw[r][b] = comp[r * NB + b];
#pragma unroll
    for (int t = 0; t < 4; ++t) {
        int k = k0 + t;
        float v = 0.f;
        if (c < dout_real) {
            if (k < 256) {
                v = root[k * dout_real + c];
            } else {
                int r = (k - 256) >> 8;
                int i = (k - 256) & 255;
#pragma unroll
                for (int b = 0; b < NB; ++b)
                    v += cw[r][b] * basis[(b * 256 + i) * dout_real + c];
            }
        }
        u32 pk = pack_split(v);
        Wt[(size_t)c * 1536 + k] = (u16)(pk >> 16);
        Wt[(size_t)c * 1536 + 768 + k] = (u16)(pk & 0xFFFFu);
    }
}

// ---------------------------------------------------------------------------
// x (fp32 [N][256]) -> two-plane rows [hi 256 | lo 256] u16
// ---------------------------------------------------------------------------
__global__ void convert_x(const float* __restrict__ x, u16* __restrict__ xP, int n2) {
    int g = blockIdx.x * 256 + threadIdx.x;  // handles 2 consecutive elems
    if (g >= n2) return;
    int i = g * 2;
    int row = i >> 8, f = i & 255;
    u32 p0 = pack_split(x[i]);
    u32 p1 = pack_split(x[i + 1]);
    *(u32*)&xP[(size_t)row * 512 + f] = (p0 >> 16) | (p1 & 0xFFFF0000u);
    *(u32*)&xP[(size_t)row * 512 + 256 + f] = (p0 & 0xFFFFu) | (p1 << 16);
}

// ---------------------------------------------------------------------------
// Aggregation: one WAVE per (node,rel); lane owns 4 features.
// In rows: [hi256|lo256] u16 (stride 512). Out rows: [hi512|lo512] (stride 1024).
// ---------------------------------------------------------------------------
__global__ __launch_bounds__(256) void agg_wave(const u16* __restrict__ hP,
                                                const int* __restrict__ cnt,
                                                const int* __restrict__ elist,
                                                u16* __restrict__ aggP, int M2) {
    int wid = blockIdx.x * 4 + (threadIdx.x >> 6);
    if (wid >= M2) return;
    int lane = threadIdx.x & 63;
    int c = cnt[wid];
    int cc = min(c, CAP);
    const int* ep = elist + (size_t)wid * CAP;
    int fo = lane << 2;  // u16 offset of this lane's 4 features (hi plane)

    float a0 = 0.f, a1 = 0.f, a2 = 0.f, a3 = 0.f;
    float b0 = 0.f, b1 = 0.f, b2 = 0.f, b3 = 0.f;

    int j = 0;
    for (; j + 1 < cc; j += 2) {
        int e0 = ep[j], e1 = ep[j + 1];
        const u16* r0 = hP + (size_t)e0 * 512;
        const u16* r1 = hP + (size_t)e1 * 512;
        uint2 h0 = *(const uint2*)(r0 + fo);
        uint2 l0 = *(const uint2*)(r0 + 256 + fo);
        uint2 h1 = *(const uint2*)(r1 + fo);
        uint2 l1 = *(const uint2*)(r1 + 256 + fo);
        a0 += bfbits(h0.x << 16) + bfbits(l0.x << 16);
        a1 += bfbits(h0.x & 0xFFFF0000u) + bfbits(l0.x & 0xFFFF0000u);
        a2 += bfbits(h0.y << 16) + bfbits(l0.y << 16);
        a3 += bfbits(h0.y & 0xFFFF0000u) + bfbits(l0.y & 0xFFFF0000u);
        b0 += bfbits(h1.x << 16) + bfbits(l1.x << 16);
        b1 += bfbits(h1.x & 0xFFFF0000u) + bfbits(l1.x & 0xFFFF0000u);
        b2 += bfbits(h1.y << 16) + bfbits(l1.y << 16);
        b3 += bfbits(h1.y & 0xFFFF0000u) + bfbits(l1.y & 0xFFFF0000u);
    }
    if (j < cc) {
        int e0 = ep[j];
        const u16* r0 = hP + (size_t)e0 * 512;
        uint2 h0 = *(const uint2*)(r0 + fo);
        uint2 l0 = *(const uint2*)(r0 + 256 + fo);
        a0 += bfbits(h0.x << 16) + bfbits(l0.x << 16);
        a1 += bfbits(h0.x & 0xFFFF0000u) + bfbits(l0.x & 0xFFFF0000u);
        a2 += bfbits(h0.y << 16) + bfbits(l0.y << 16);
        a3 += bfbits(h0.y & 0xFFFF0000u) + bfbits(l0.y & 0xFFFF0000u);
    }
    a0 += b0; a1 += b1; a2 += b2; a3 += b3;

    float inv = (c > 0) ? 1.f / (float)c : 0.f;
    u32 p0 = pack_split(a0 * inv);
    u32 p1 = pack_split(a1 * inv);
    u32 p2 = pack_split(a2 * inv);
    u32 p3 = pack_split(a3 * inv);

    int n = wid >> 1, r = wid & 1;
    u16* orow = aggP + (size_t)n * 1024 + r * 256 + fo;
    uint2 hw, lw;
    hw.x = (p0 >> 16) | (p1 & 0xFFFF0000u);
    hw.y = (p2 >> 16) | (p3 & 0xFFFF0000u);
    lw.x = (p0 & 0xFFFFu) | (p1 << 16);
    lw.y = (p2 & 0xFFFFu) | (p3 << 16);
    *(uint2*)orow = hw;
    *(uint2*)(orow + 512) = lw;
}

// ---------------------------------------------------------------------------
// MFMA GEMM (layers 1,2): Out[M][256] = relu([A0|A1](M x 768) @ W + bias)
// A0 rows: [hi256|lo256] (stride 512 u16); A1 rows: [hi512|lo512] (stride 1024).
// Wt rows (per col c): [hi768|lo768] (stride 1536). Out rows like A0.
// Block 64r x 128c, 4 waves (2x2); W k-chunk(32) in LDS (80B pitch, conflict-free).
// ---------------------------------------------------------------------------
__global__ __launch_bounds__(256) void gemm_mfma_big(
    const u16* __restrict__ A0, const u16* __restrict__ A1,
    const u16* __restrict__ Wt, const float* __restrict__ bias,
    u16* __restrict__ OutP, int M) {
    __shared__ u16 ldsB[2][128][40];
    int tid = threadIdx.x;
    int lane = tid & 63;
    int w = tid >> 6;
    int wr = w >> 1, wc = w & 1;
    int rb0 = blockIdx.y * 64;
    int cb0 = blockIdx.x * 128;
    int l15 = lane & 15, l4 = lane >> 4;
    int arow0 = rb0 + wr * 32 + l15;

    int su_col[2], su_u[2];
#pragma unroll
    for (int i = 0; i < 2; ++i) {
        int unit = i * 256 + tid;
        su_col[i] = unit >> 2;
        su_u[i] = unit & 3;
    }

    f32x4 acc[2][4] = {};
    uint4 wh[2], wl[2];

    // prefetch W chunk 0
#pragma unroll
    for (int i = 0; i < 2; ++i) {
        const u16* base = Wt + (size_t)(cb0 + su_col[i]) * 1536 + su_u[i] * 8;
        wh[i] = *(const uint4*)base;
        wl[i] = *(const uint4*)(base + 768);
    }

    for (int kk = 0; kk < 768; kk += 32) {
        // A fragments for this k-chunk (global, two-plane -> direct bf16x8)
        bf16x8 ah[2], al[2];
#pragma unroll
        for (int rt = 0; rt < 2; ++rt) {
            int r = arow0 + rt * 16;
            const u16* hib;
            const u16* lob;
            if (kk < 256) {
                hib = A0 + (size_t)r * 512 + kk + l4 * 8;
                lob = hib + 256;
            } else {
                hib = A1 + (size_t)r * 1024 + (kk - 256) + l4 * 8;
                lob = hib + 512;
            }
            ah[rt] = *(const bf16x8*)hib;
            al[rt] = *(const bf16x8*)lob;
        }

        __syncthreads();
        // write prefetched W regs to LDS
#pragma unroll
        for (int i = 0; i < 2; ++i) {
            *(uint4*)&ldsB[0][su_col[i]][su_u[i] * 8] = wh[i];
            *(uint4*)&ldsB[1][su_col[i]][su_u[i] * 8] = wl[i];
        }
        __syncthreads();
        // prefetch next W chunk
        if (kk + 32 < 768) {
#pragma unroll
            for (int i = 0; i < 2; ++i) {
                const u16* base = Wt + (size_t)(cb0 + su_col[i]) * 1536 + (kk + 32) + su_u[i] * 8;
                wh[i] = *(const uint4*)base;
                wl[i] = *(const uint4*)(base + 768);
            }
        }

#pragma unroll
        for (int ct = 0; ct < 4; ++ct) {
            int col = wc * 64 + ct * 16 + l15;
            bf16x8 bh = *(const bf16x8*)&ldsB[0][col][l4 * 8];
            bf16x8 bl = *(const bf16x8*)&ldsB[1][col][l4 * 8];
#pragma unroll
            for (int rt = 0; rt < 2; ++rt) {
                acc[rt][ct] = MFMA16(ah[rt], bh, acc[rt][ct], 0, 0, 0);
                acc[rt][ct] = MFMA16(ah[rt], bl, acc[rt][ct], 0, 0, 0);
                acc[rt][ct] = MFMA16(al[rt], bh, acc[rt][ct], 0, 0, 0);
            }
        }
    }

    // epilogue: bias + relu + split-pack to two planes
#pragma unroll
    for (int rt = 0; rt < 2; ++rt) {
#pragma unroll
        for (int ct = 0; ct < 4; ++ct) {
            int col = cb0 + wc * 64 + ct * 16 + l15;
            float b = bias[col];
#pragma unroll
            for (int j = 0; j < 4; ++j) {
                int row = rb0 + wr * 32 + rt * 16 + l4 * 4 + j;
                if (row < M) {
                    float v = fmaxf(acc[rt][ct][j] + b, 0.f);
                    u32 pk = pack_split(v);
                    OutP[(size_t)row * 512 + col] = (u16)(pk >> 16);
                    OutP[(size_t)row * 512 + 256 + col] = (u16)(pk & 0xFFFFu);
                }
            }
        }
    }
}

// ---------------------------------------------------------------------------
// MFMA GEMM (layer 3) + fused log_softmax: Out[M][40] fp32
// W3 padded to 48 cols (3 frags); B-frags direct from global (L2-resident).
// ---------------------------------------------------------------------------
__global__ __launch_bounds__(256) void gemm_mfma_small(
    const u16* __restrict__ A0, const u16* __restrict__ A1,
    const u16* __restrict__ Wt, const float* __restrict__ bias,
    float* __restrict__ Out, int M) {
    int tid = threadIdx.x;
    int lane = tid & 63;
    int w = tid >> 6;
    int l15 = lane & 15, l4 = lane >> 4;
    int row0 = blockIdx.x * 64 + w * 16;
    int arow = row0 + l15;

    f32x4 acc[3] = {};

    for (int kk = 0; kk < 768; kk += 32) {
        const u16* hib;
        const u16* lob;
        if (kk < 256) {
            hib = A0 + (size_t)arow * 512 + kk + l4 * 8;
            lob = hib + 256;
        } else {
            hib = A1 + (size_t)arow * 1024 + (kk - 256) + l4 * 8;
            lob = hib + 512;
        }
        bf16x8 ah = *(const bf16x8*)hib;
        bf16x8 al = *(const bf16x8*)lob;
#pragma unroll
        for (int ct = 0; ct < 3; ++ct) {
            const u16* wb = Wt + (size_t)(ct * 16 + l15) * 1536 + kk + l4 * 8;
            bf16x8 bh = *(const bf16x8*)wb;
            bf16x8 bl = *(const bf16x8*)(wb + 768);
            acc[ct] = MFMA16(ah, bh, acc[ct], 0, 0, 0);
            acc[ct] = MFMA16(ah, bl, acc[ct], 0, 0, 0);
            acc[ct] = MFMA16(al, bh, acc[ct], 0, 0, 0);
        }
    }

    bool val2 = (l15 < 8);  // ct=2 -> cols 32..47, valid only <40
    float bq0 = bias[l15];
    float bq1 = bias[16 + l15];
    float bq2 = val2 ? bias[32 + l15] : 0.f;

#pragma unroll
    for (int j = 0; j < 4; ++j) {
        float v0 = acc[0][j] + bq0;
        float v1 = acc[1][j] + bq1;
        float v2 = val2 ? (acc[2][j] + bq2) : -INFINITY;
        float m = fmaxf(fmaxf(v0, v1), v2);
#pragma unroll
        for (int d = 1; d < 16; d <<= 1) m = fmaxf(m, __shfl_xor(m, d, 64));
        float s = expf(v0 - m) + expf(v1 - m) + (val2 ? expf(v2 - m) : 0.f);
#pragma unroll
        for (int d = 1; d < 16; d <<= 1) s += __shfl_xor(s, d, 64);
        float ls = m + logf(s);
        int row = row0 + l4 * 4 + j;
        if (row < M) {
            Out[(size_t)row * C_OUT + l15] = v0 - ls;
            Out[(size_t)row * C_OUT + 16 + l15] = v1 - ls;
            if (val2) Out[(size_t)row * C_OUT + 32 + l15] = v2 - ls;
        }
    }
}

// ---------------------------------------------------------------------------
extern "C" void kernel_launch(void* const* d_in, const int* in_sizes, int n_in,
                              void* d_out, int out_size, void* d_ws, size_t ws_size,
                              hipStream_t stream) {
    const float* x = (const float*)d_in[0];
    const int* ei = (const int*)d_in[1];
    const int* et = (const int*)d_in[2];
    const float* basis1 = (const float*)d_in[3];
    const float* comp1 = (const float*)d_in[4];
    const float* root1 = (const float*)d_in[5];
    const float* bias1 = (const float*)d_in[6];
    const float* basis2 = (const float*)d_in[7];
    const float* comp2 = (const float*)d_in[8];
    const float* root2 = (const float*)d_in[9];
    const float* bias2 = (const float*)d_in[10];
    const float* basis3 = (const float*)d_in[11];
    const float* comp3 = (const float*)d_in[12];
    const float* root3 = (const float*)d_in[13];
    const float* bias3 = (const float*)d_in[14];

    int N_ = in_sizes[0] / 256;
    int E_ = in_sizes[2];
    int M2 = 2 * N_;
    int Mpad = (N_ + 63) & ~63;

    char* p = (char*)d_ws;
    size_t o = 0;
    auto alloc = [&](size_t bytes) {
        void* r = p + o;
        o += (bytes + 255) & ~(size_t)255;
        return r;
    };
    int* cnt = (int*)alloc((size_t)M2 * 4);
    int* elist = (int*)alloc((size_t)M2 * CAP * 4);
    u16* Wt1 = (u16*)alloc((size_t)256 * 1536 * 2);
    u16* Wt2 = (u16*)alloc((size_t)256 * 1536 * 2);
    u16* Wt3 = (u16*)alloc((size_t)48 * 1536 * 2);
    u16* xP = (u16*)alloc((size_t)Mpad * 512 * 2);
    u16* h1P = (u16*)alloc((size_t)Mpad * 512 * 2);
    u16* aggP = (u16*)alloc((size_t)Mpad * 1024 * 2);
    u16* h2P = xP;  // x dead after layer 1
    (void)ws_size;

    // CSR (capacity-64 bump alloc; no count/scan)
    zero_i32<<<(M2 + 255) / 256, 256, 0, stream>>>(cnt, M2);
    fill_edges_cap<<<(E_ + 255) / 256, 256, 0, stream>>>(ei, et, cnt, elist, E_);

    // weights (coalesced build, two-plane)
    build_wt_coal<<<192, 256, 0, stream>>>(basis1, comp1, root1, Wt1, 256);
    build_wt_coal<<<192, 256, 0, stream>>>(basis2, comp2, root2, Wt2, 256);
    build_wt_coal<<<192, 64, 0, stream>>>(basis3, comp3, root3, Wt3, 40);

    convert_x<<<(N_ * 128 + 255) / 256, 256, 0, stream>>>(x, xP, N_ * 128);

    int mblocks = (N_ + 63) / 64;
    int ablocks = (M2 + 3) / 4;

    // layer 1
    agg_wave<<<ablocks, 256, 0, stream>>>(xP, cnt, elist, aggP, M2);
    {
        dim3 g(2, mblocks);
        gemm_mfma_big<<<g, 256, 0, stream>>>(xP, aggP, Wt1, bias1, h1P, N_);
    }
    // layer 2
    agg_wave<<<ablocks, 256, 0, stream>>>(h1P, cnt, elist, aggP, M2);
    {
        dim3 g(2, mblocks);
        gemm_mfma_big<<<g, 256, 0, stream>>>(h1P, aggP, Wt2, bias2, h2P, N_);
    }
    // layer 3 (+ fused log_softmax)
    agg_wave<<<ablocks, 256, 0, stream>>>(h2P, cnt, elist, aggP, M2);
    gemm_mfma_small<<<mblocks, 256, 0, stream>>>(h2P, aggP, Wt3, bias3, (float*)d_out, N_);
}

// Round 4
// 282.710 us; speedup vs baseline: 1.2206x; 1.2206x over previous
//
#include <hip/hip_runtime.h>
#include <math.h>

#define NREL 2
#define NB 10
#define C_OUT 40
#define CAP 64  // per-(node,rel) capacity; degrees ~Poisson(16), P(>64)~1e-19

typedef unsigned int u32;
typedef unsigned short u16;
typedef __attribute__((ext_vector_type(8))) short bf16x8;
typedef __attribute__((ext_vector_type(4))) float f32x4;

#define MFMA16 __builtin_amdgcn_mfma_f32_16x16x32_bf16

// split-bf16: v ~= bf16(v) + bf16(v - bf16(v)); returns (hi16<<16)|lo16
__device__ __forceinline__ u32 pack_split(float v) {
    u32 u = __float_as_uint(v);
    u32 hi = (u + 0x7FFFu + ((u >> 16) & 1u)) & 0xFFFF0000u;  // RNE to bf16
    float r = v - __uint_as_float(hi);
    u32 ur = __float_as_uint(r);
    u32 lo = ((ur + 0x7FFFu + ((ur >> 16) & 1u)) >> 16) & 0xFFFFu;
    return hi | lo;
}
__device__ __forceinline__ float bfbits(u32 w) { return __uint_as_float(w); }

// ---------------------------------------------------------------------------
// CSR build: capacity-64 bump allocation
// ---------------------------------------------------------------------------
__global__ void zero_i32(int* __restrict__ p, int n) {
    int i = blockIdx.x * 256 + threadIdx.x;
    if (i < n) p[i] = 0;
}

__global__ void fill_edges_cap(const int* __restrict__ ei, const int* __restrict__ et,
                               int* __restrict__ cnt, int* __restrict__ elist, int E_) {
    int e = blockIdx.x * 256 + threadIdx.x;
    if (e < E_) {
        int src = ei[e];
        int dst = ei[E_ + e];
        int r = et[e];
        int idx = dst * 2 + r;
        int pos = atomicAdd(&cnt[idx], 1);
        if (pos < CAP) elist[idx * CAP + pos] = src;
    }
}

// ---------------------------------------------------------------------------
// Weight build (coalesced): Wt row c = [hi(768) | lo(768)] u16, k: root|W0|W1
// ---------------------------------------------------------------------------
__global__ void build_wt_coal(const float* __restrict__ basis, const float* __restrict__ comp,
                              const float* __restrict__ root, u16* __restrict__ Wt,
                              int dout_real) {
    int c = threadIdx.x;
    int k0 = blockIdx.x * 4;
    float cw[NREL][NB];
#pragma unroll
    for (int r = 0; r < NREL; ++r)
#pragma unroll
        for (int b = 0; b < NB; ++b) cw[r][b] = comp[r * NB + b];
#pragma unroll
    for (int t = 0; t < 4; ++t) {
        int k = k0 + t;
        float v = 0.f;
        if (c < dout_real) {
            if (k < 256) {
                v = root[k * dout_real + c];
            } else {
                int r = (k - 256) >> 8;
                int i = (k - 256) & 255;
#pragma unroll
                for (int b = 0; b < NB; ++b)
                    v += cw[r][b] * basis[(b * 256 + i) * dout_real + c];
            }
        }
        u32 pk = pack_split(v);
        Wt[(size_t)c * 1536 + k] = (u16)(pk >> 16);
        Wt[(size_t)c * 1536 + 768 + k] = (u16)(pk & 0xFFFFu);
    }
}

// ---------------------------------------------------------------------------
// x (fp32 [N][256]) -> two-plane rows [hi 256 | lo 256] u16
// ---------------------------------------------------------------------------
__global__ void convert_x(const float* __restrict__ x, u16* __restrict__ xP, int n2) {
    int g = blockIdx.x * 256 + threadIdx.x;
    if (g >= n2) return;
    int i = g * 2;
    int row = i >> 8, f = i & 255;
    u32 p0 = pack_split(x[i]);
    u32 p1 = pack_split(x[i + 1]);
    *(u32*)&xP[(size_t)row * 512 + f] = (p0 >> 16) | (p1 & 0xFFFF0000u);
    *(u32*)&xP[(size_t)row * 512 + 256 + f] = (p0 & 0xFFFFu) | (p1 << 16);
}

// ---------------------------------------------------------------------------
// Aggregation: one WAVE per (node,rel); lane owns 4 features; gathers HI plane
// only (bf16 inputs, fp32 accumulate), writes split-packed mean.
// In rows: [hi256|lo256] (stride 512). Out rows: [hi512|lo512] (stride 1024).
// ---------------------------------------------------------------------------
__global__ __launch_bounds__(256) void agg_wave(const u16* __restrict__ hP,
                                                const int* __restrict__ cnt,
                                                const int* __restrict__ elist,
                                                u16* __restrict__ aggP, int M2) {
    int wid = blockIdx.x * 4 + (threadIdx.x >> 6);
    if (wid >= M2) return;
    int lane = threadIdx.x & 63;
    int c = cnt[wid];
    int cc = min(c, CAP);
    const int* ep = elist + (size_t)wid * CAP;
    int fo = lane << 2;  // u16 offset of this lane's 4 features

    float s0 = 0.f, s1 = 0.f, s2 = 0.f, s3 = 0.f;
    int j = 0;
    for (; j + 3 < cc; j += 4) {
        int e0 = ep[j], e1 = ep[j + 1], e2 = ep[j + 2], e3 = ep[j + 3];
        uint2 h0 = *(const uint2*)(hP + (size_t)e0 * 512 + fo);
        uint2 h1 = *(const uint2*)(hP + (size_t)e1 * 512 + fo);
        uint2 h2 = *(const uint2*)(hP + (size_t)e2 * 512 + fo);
        uint2 h3 = *(const uint2*)(hP + (size_t)e3 * 512 + fo);
        s0 += bfbits(h0.x << 16) + bfbits(h1.x << 16) + bfbits(h2.x << 16) + bfbits(h3.x << 16);
        s1 += bfbits(h0.x & 0xFFFF0000u) + bfbits(h1.x & 0xFFFF0000u) +
              bfbits(h2.x & 0xFFFF0000u) + bfbits(h3.x & 0xFFFF0000u);
        s2 += bfbits(h0.y << 16) + bfbits(h1.y << 16) + bfbits(h2.y << 16) + bfbits(h3.y << 16);
        s3 += bfbits(h0.y & 0xFFFF0000u) + bfbits(h1.y & 0xFFFF0000u) +
              bfbits(h2.y & 0xFFFF0000u) + bfbits(h3.y & 0xFFFF0000u);
    }
    for (; j < cc; ++j) {
        uint2 h0 = *(const uint2*)(hP + (size_t)ep[j] * 512 + fo);
        s0 += bfbits(h0.x << 16);
        s1 += bfbits(h0.x & 0xFFFF0000u);
        s2 += bfbits(h0.y << 16);
        s3 += bfbits(h0.y & 0xFFFF0000u);
    }

    float inv = (c > 0) ? 1.f / (float)c : 0.f;
    u32 p0 = pack_split(s0 * inv);
    u32 p1 = pack_split(s1 * inv);
    u32 p2 = pack_split(s2 * inv);
    u32 p3 = pack_split(s3 * inv);

    int n = wid >> 1, r = wid & 1;
    u16* orow = aggP + (size_t)n * 1024 + r * 256 + fo;
    uint2 hw, lw;
    hw.x = (p0 >> 16) | (p1 & 0xFFFF0000u);
    hw.y = (p2 >> 16) | (p3 & 0xFFFF0000u);
    lw.x = (p0 & 0xFFFFu) | (p1 << 16);
    lw.y = (p2 & 0xFFFFu) | (p3 << 16);
    *(uint2*)orow = hw;
    *(uint2*)(orow + 512) = lw;
}

// ---------------------------------------------------------------------------
// MFMA GEMM (layers 1,2), barrier-free: Out[M][256] = relu([A0|A1] @ W + bias)
// Block: 4 independent waves; wave = 32 rows x 64 cols (acc 2x4 frags).
// Grid = ceil(M/32). B-frags direct from L2 (W is 0.75MB, L2-resident).
// ---------------------------------------------------------------------------
__global__ __launch_bounds__(256) void gemm_mfma_big(
    const u16* __restrict__ A0, const u16* __restrict__ A1,
    const u16* __restrict__ Wt, const float* __restrict__ bias,
    u16* __restrict__ OutP, int M) {
    int tid = threadIdx.x;
    int lane = tid & 63;
    int w = tid >> 6;  // col-group: cols w*64 .. w*64+63
    int l15 = lane & 15, l4 = lane >> 4;
    int rb0 = blockIdx.x * 32;
    int arow0 = rb0 + l15;

    f32x4 acc[2][4] = {};

#pragma unroll 2
    for (int kk = 0; kk < 768; kk += 32) {
        bf16x8 ah[2], al[2];
#pragma unroll
        for (int rt = 0; rt < 2; ++rt) {
            int r = arow0 + rt * 16;
            const u16* hib;
            if (kk < 256) {
                hib = A0 + (size_t)r * 512 + kk + l4 * 8;
                al[rt] = *(const bf16x8*)(hib + 256);
            } else {
                hib = A1 + (size_t)r * 1024 + (kk - 256) + l4 * 8;
                al[rt] = *(const bf16x8*)(hib + 512);
            }
            ah[rt] = *(const bf16x8*)hib;
        }
        bf16x8 bh[4], bl[4];
#pragma unroll
        for (int ct = 0; ct < 4; ++ct) {
            const u16* wb = Wt + (size_t)(w * 64 + ct * 16 + l15) * 1536 + kk + l4 * 8;
            bh[ct] = *(const bf16x8*)wb;
            bl[ct] = *(const bf16x8*)(wb + 768);
        }
#pragma unroll
        for (int ct = 0; ct < 4; ++ct) {
#pragma unroll
            for (int rt = 0; rt < 2; ++rt) {
                acc[rt][ct] = MFMA16(ah[rt], bh[ct], acc[rt][ct], 0, 0, 0);
                acc[rt][ct] = MFMA16(ah[rt], bl[ct], acc[rt][ct], 0, 0, 0);
                acc[rt][ct] = MFMA16(al[rt], bh[ct], acc[rt][ct], 0, 0, 0);
            }
        }
    }

    // epilogue: bias + relu + split-pack to two planes
#pragma unroll
    for (int rt = 0; rt < 2; ++rt) {
#pragma unroll
        for (int ct = 0; ct < 4; ++ct) {
            int col = w * 64 + ct * 16 + l15;
            float b = bias[col];
#pragma unroll
            for (int j = 0; j < 4; ++j) {
                int row = rb0 + rt * 16 + l4 * 4 + j;
                if (row < M) {
                    float v = fmaxf(acc[rt][ct][j] + b, 0.f);
                    u32 pk = pack_split(v);
                    OutP[(size_t)row * 512 + col] = (u16)(pk >> 16);
                    OutP[(size_t)row * 512 + 256 + col] = (u16)(pk & 0xFFFFu);
                }
            }
        }
    }
}

// ---------------------------------------------------------------------------
// MFMA GEMM (layer 3) + fused log_softmax: Out[M][40] fp32, 2 waves/block
// ---------------------------------------------------------------------------
__global__ __launch_bounds__(128) void gemm_mfma_small(
    const u16* __restrict__ A0, const u16* __restrict__ A1,
    const u16* __restrict__ Wt, const float* __restrict__ bias,
    float* __restrict__ Out, int M) {
    int tid = threadIdx.x;
    int lane = tid & 63;
    int w = tid >> 6;
    int l15 = lane & 15, l4 = lane >> 4;
    int row0 = blockIdx.x * 32 + w * 16;
    int arow = row0 + l15;

    f32x4 acc[3] = {};

#pragma unroll 2
    for (int kk = 0; kk < 768; kk += 32) {
        const u16* hib;
        bf16x8 al;
        if (kk < 256) {
            hib = A0 + (size_t)arow * 512 + kk + l4 * 8;
            al = *(const bf16x8*)(hib + 256);
        } else {
            hib = A1 + (size_t)arow * 1024 + (kk - 256) + l4 * 8;
            al = *(const bf16x8*)(hib + 512);
        }
        bf16x8 ah = *(const bf16x8*)hib;
#pragma unroll
        for (int ct = 0; ct < 3; ++ct) {
            const u16* wb = Wt + (size_t)(ct * 16 + l15) * 1536 + kk + l4 * 8;
            bf16x8 bh = *(const bf16x8*)wb;
            bf16x8 bl = *(const bf16x8*)(wb + 768);
            acc[ct] = MFMA16(ah, bh, acc[ct], 0, 0, 0);
            acc[ct] = MFMA16(ah, bl, acc[ct], 0, 0, 0);
            acc[ct] = MFMA16(al, bh, acc[ct], 0, 0, 0);
        }
    }

    bool val2 = (l15 < 8);
    float bq0 = bias[l15];
    float bq1 = bias[16 + l15];
    float bq2 = val2 ? bias[32 + l15] : 0.f;

#pragma unroll
    for (int j = 0; j < 4; ++j) {
        float v0 = acc[0][j] + bq0;
        float v1 = acc[1][j] + bq1;
        float v2 = val2 ? (acc[2][j] + bq2) : -INFINITY;
        float m = fmaxf(fmaxf(v0, v1), v2);
#pragma unroll
        for (int d = 1; d < 16; d <<= 1) m = fmaxf(m, __shfl_xor(m, d, 64));
        float s = expf(v0 - m) + expf(v1 - m) + (val2 ? expf(v2 - m) : 0.f);
#pragma unroll
        for (int d = 1; d < 16; d <<= 1) s += __shfl_xor(s, d, 64);
        float ls = m + logf(s);
        int row = row0 + l4 * 4 + j;
        if (row < M) {
            Out[(size_t)row * C_OUT + l15] = v0 - ls;
            Out[(size_t)row * C_OUT + 16 + l15] = v1 - ls;
            if (val2) Out[(size_t)row * C_OUT + 32 + l15] = v2 - ls;
        }
    }
}

// ---------------------------------------------------------------------------
extern "C" void kernel_launch(void* const* d_in, const int* in_sizes, int n_in,
                              void* d_out, int out_size, void* d_ws, size_t ws_size,
                              hipStream_t stream) {
    const float* x = (const float*)d_in[0];
    const int* ei = (const int*)d_in[1];
    const int* et = (const int*)d_in[2];
    const float* basis1 = (const float*)d_in[3];
    const float* comp1 = (const float*)d_in[4];
    const float* root1 = (const float*)d_in[5];
    const float* bias1 = (const float*)d_in[6];
    const float* basis2 = (const float*)d_in[7];
    const float* comp2 = (const float*)d_in[8];
    const float* root2 = (const float*)d_in[9];
    const float* bias2 = (const float*)d_in[10];
    const float* basis3 = (const float*)d_in[11];
    const float* comp3 = (const float*)d_in[12];
    const float* root3 = (const float*)d_in[13];
    const float* bias3 = (const float*)d_in[14];

    int N_ = in_sizes[0] / 256;
    int E_ = in_sizes[2];
    int M2 = 2 * N_;
    int Mpad = (N_ + 63) & ~63;

    char* p = (char*)d_ws;
    size_t o = 0;
    auto alloc = [&](size_t bytes) {
        void* r = p + o;
        o += (bytes + 255) & ~(size_t)255;
        return r;
    };
    int* cnt = (int*)alloc((size_t)M2 * 4);
    int* elist = (int*)alloc((size_t)M2 * CAP * 4);
    u16* Wt1 = (u16*)alloc((size_t)256 * 1536 * 2);
    u16* Wt2 = (u16*)alloc((size_t)256 * 1536 * 2);
    u16* Wt3 = (u16*)alloc((size_t)48 * 1536 * 2);
    u16* xP = (u16*)alloc((size_t)Mpad * 512 * 2);
    u16* h1P = (u16*)alloc((size_t)Mpad * 512 * 2);
    u16* aggP = (u16*)alloc((size_t)Mpad * 1024 * 2);
    u16* h2P = xP;  // x dead after layer 1
    (void)ws_size;

    // CSR
    zero_i32<<<(M2 + 255) / 256, 256, 0, stream>>>(cnt, M2);
    fill_edges_cap<<<(E_ + 255) / 256, 256, 0, stream>>>(ei, et, cnt, elist, E_);

    // weights
    build_wt_coal<<<192, 256, 0, stream>>>(basis1, comp1, root1, Wt1, 256);
    build_wt_coal<<<192, 256, 0, stream>>>(basis2, comp2, root2, Wt2, 256);
    build_wt_coal<<<192, 64, 0, stream>>>(basis3, comp3, root3, Wt3, 40);

    convert_x<<<(N_ * 128 + 255) / 256, 256, 0, stream>>>(x, xP, N_ * 128);

    int gblocks = (N_ + 31) / 32;
    int ablocks = (M2 + 3) / 4;

    // layer 1
    agg_wave<<<ablocks, 256, 0, stream>>>(xP, cnt, elist, aggP, M2);
    gemm_mfma_big<<<gblocks, 256, 0, stream>>>(xP, aggP, Wt1, bias1, h1P, N_);
    // layer 2
    agg_wave<<<ablocks, 256, 0, stream>>>(h1P, cnt, elist, aggP, M2);
    gemm_mfma_big<<<gblocks, 256, 0, stream>>>(h1P, aggP, Wt2, bias2, h2P, N_);
    // layer 3 (+ fused log_softmax)
    agg_wave<<<ablocks, 256, 0, stream>>>(h2P, cnt, elist, aggP, M2);
    gemm_mfma_small<<<gblocks, 128, 0, stream>>>(h2P, aggP, Wt3, bias3, (float*)d_out, N_);
}

// Round 5
// 235.840 us; speedup vs baseline: 1.4631x; 1.1987x over previous
//
#include <hip/hip_runtime.h>
#include <math.h>

#define NREL 2
#define NB 10
#define C_OUT 40
#define CAP 64  // per-(node,rel) capacity; degrees ~Poisson(16), P(>64)~1e-19

typedef unsigned int u32;
typedef unsigned short u16;
typedef __attribute__((ext_vector_type(8))) short bf16x8;
typedef __attribute__((ext_vector_type(4))) float f32x4;

#define MFMA16 __builtin_amdgcn_mfma_f32_16x16x32_bf16

// split-bf16: v ~= bf16(v) + bf16(v - bf16(v)); returns (hi16<<16)|lo16
__device__ __forceinline__ u32 pack_split(float v) {
    u32 u = __float_as_uint(v);
    u32 hi = (u + 0x7FFFu + ((u >> 16) & 1u)) & 0xFFFF0000u;  // RNE to bf16
    float r = v - __uint_as_float(hi);
    u32 ur = __float_as_uint(r);
    u32 lo = ((ur + 0x7FFFu + ((ur >> 16) & 1u)) >> 16) & 0xFFFFu;
    return hi | lo;
}
__device__ __forceinline__ float bfbits(u32 w) { return __uint_as_float(w); }

// ---------------------------------------------------------------------------
// CSR build: capacity-64 bump allocation
// ---------------------------------------------------------------------------
__global__ void zero_i32(int* __restrict__ p, int n) {
    int i = blockIdx.x * 256 + threadIdx.x;
    if (i < n) p[i] = 0;
}

__global__ void fill_edges_cap(const int* __restrict__ ei, const int* __restrict__ et,
                               int* __restrict__ cnt, int* __restrict__ elist, int E_) {
    int e = blockIdx.x * 256 + threadIdx.x;
    if (e < E_) {
        int src = ei[e];
        int dst = ei[E_ + e];
        int r = et[e];
        int idx = dst * 2 + r;
        int pos = atomicAdd(&cnt[idx], 1);
        if (pos < CAP) elist[idx * CAP + pos] = src;
    }
}

// ---------------------------------------------------------------------------
// Weight build, all 3 layers in one dispatch (blockIdx.y = layer).
// Wt row c = [hi(768) | lo(768)] u16, k: root|W0|W1, coalesced over c.
// ---------------------------------------------------------------------------
__global__ void build_wt_all(const float* __restrict__ basis1, const float* __restrict__ comp1,
                             const float* __restrict__ root1, u16* __restrict__ Wt1,
                             const float* __restrict__ basis2, const float* __restrict__ comp2,
                             const float* __restrict__ root2, u16* __restrict__ Wt2,
                             const float* __restrict__ basis3, const float* __restrict__ comp3,
                             const float* __restrict__ root3, u16* __restrict__ Wt3) {
    int layer = blockIdx.y;
    const float* basis = (layer == 0) ? basis1 : (layer == 1) ? basis2 : basis3;
    const float* comp = (layer == 0) ? comp1 : (layer == 1) ? comp2 : comp3;
    const float* root = (layer == 0) ? root1 : (layer == 1) ? root2 : root3;
    u16* Wt = (layer == 0) ? Wt1 : (layer == 1) ? Wt2 : Wt3;
    int dreal = (layer == 2) ? C_OUT : 256;
    int dpad = (layer == 2) ? 48 : 256;

    int c = threadIdx.x;
    if (c >= dpad) return;
    int k0 = blockIdx.x * 4;
    float cw[NREL][NB];
#pragma unroll
    for (int r = 0; r < NREL; ++r)
#pragma unroll
        for (int b = 0; b < NB; ++b) cw[r][b] = comp[r * NB + b];
#pragma unroll
    for (int t = 0; t < 4; ++t) {
        int k = k0 + t;
        float v = 0.f;
        if (c < dreal) {
            if (k < 256) {
                v = root[k * dreal + c];
            } else {
                int r = (k - 256) >> 8;
                int i = (k - 256) & 255;
#pragma unroll
                for (int b = 0; b < NB; ++b)
                    v += cw[r][b] * basis[(b * 256 + i) * dreal + c];
            }
        }
        u32 pk = pack_split(v);
        Wt[(size_t)c * 1536 + k] = (u16)(pk >> 16);
        Wt[(size_t)c * 1536 + 768 + k] = (u16)(pk & 0xFFFFu);
    }
}

// ---------------------------------------------------------------------------
// x (fp32 [N][256]) -> two-plane rows [hi 256 | lo 256] u16
// ---------------------------------------------------------------------------
__global__ void convert_x(const float* __restrict__ x, u16* __restrict__ xP, int n2) {
    int g = blockIdx.x * 256 + threadIdx.x;
    if (g >= n2) return;
    int i = g * 2;
    int row = i >> 8, f = i & 255;
    u32 p0 = pack_split(x[i]);
    u32 p1 = pack_split(x[i + 1]);
    *(u32*)&xP[(size_t)row * 512 + f] = (p0 >> 16) | (p1 & 0xFFFF0000u);
    *(u32*)&xP[(size_t)row * 512 + 256 + f] = (p0 & 0xFFFFu) | (p1 << 16);
}

// ---------------------------------------------------------------------------
// Aggregation: one WAVE per (node,rel); lane owns 4 features; gathers HI plane
// only (bf16 inputs, fp32 accumulate), writes split-packed mean.
// ---------------------------------------------------------------------------
__global__ __launch_bounds__(256) void agg_wave(const u16* __restrict__ hP,
                                                const int* __restrict__ cnt,
                                                const int* __restrict__ elist,
                                                u16* __restrict__ aggP, int M2) {
    int wid = blockIdx.x * 4 + (threadIdx.x >> 6);
    if (wid >= M2) return;
    int lane = threadIdx.x & 63;
    int c = cnt[wid];
    int cc = min(c, CAP);
    const int* ep = elist + (size_t)wid * CAP;
    int fo = lane << 2;

    float s0 = 0.f, s1 = 0.f, s2 = 0.f, s3 = 0.f;
    int j = 0;
    for (; j + 3 < cc; j += 4) {
        int e0 = ep[j], e1 = ep[j + 1], e2 = ep[j + 2], e3 = ep[j + 3];
        uint2 h0 = *(const uint2*)(hP + (size_t)e0 * 512 + fo);
        uint2 h1 = *(const uint2*)(hP + (size_t)e1 * 512 + fo);
        uint2 h2 = *(const uint2*)(hP + (size_t)e2 * 512 + fo);
        uint2 h3 = *(const uint2*)(hP + (size_t)e3 * 512 + fo);
        s0 += bfbits(h0.x << 16) + bfbits(h1.x << 16) + bfbits(h2.x << 16) + bfbits(h3.x << 16);
        s1 += bfbits(h0.x & 0xFFFF0000u) + bfbits(h1.x & 0xFFFF0000u) +
              bfbits(h2.x & 0xFFFF0000u) + bfbits(h3.x & 0xFFFF0000u);
        s2 += bfbits(h0.y << 16) + bfbits(h1.y << 16) + bfbits(h2.y << 16) + bfbits(h3.y << 16);
        s3 += bfbits(h0.y & 0xFFFF0000u) + bfbits(h1.y & 0xFFFF0000u) +
              bfbits(h2.y & 0xFFFF0000u) + bfbits(h3.y & 0xFFFF0000u);
    }
    for (; j < cc; ++j) {
        uint2 h0 = *(const uint2*)(hP + (size_t)ep[j] * 512 + fo);
        s0 += bfbits(h0.x << 16);
        s1 += bfbits(h0.x & 0xFFFF0000u);
        s2 += bfbits(h0.y << 16);
        s3 += bfbits(h0.y & 0xFFFF0000u);
    }

    float inv = (c > 0) ? 1.f / (float)c : 0.f;
    u32 p0 = pack_split(s0 * inv);
    u32 p1 = pack_split(s1 * inv);
    u32 p2 = pack_split(s2 * inv);
    u32 p3 = pack_split(s3 * inv);

    int n = wid >> 1, r = wid & 1;
    u16* orow = aggP + (size_t)n * 1024 + r * 256 + fo;
    uint2 hw, lw;
    hw.x = (p0 >> 16) | (p1 & 0xFFFF0000u);
    hw.y = (p2 >> 16) | (p3 & 0xFFFF0000u);
    lw.x = (p0 & 0xFFFFu) | (p1 << 16);
    lw.y = (p2 & 0xFFFFu) | (p3 << 16);
    *(uint2*)orow = hw;
    *(uint2*)(orow + 512) = lw;
}

// ---------------------------------------------------------------------------
// MFMA GEMM (layers 1,2), barrier-free, branchless, latency-optimized.
// Wave = 16 rows x 64 cols (acc 4 frags); block = 4 waves (all 256 cols);
// grid = ceil(M/16) -> 2500 waves (TLP). Two fully-unrolled phases (A0: k<256,
// A1: k>=256) -> compiler software-pipelines loads. 2-product split: (ah+al)*bh.
// ---------------------------------------------------------------------------
__global__ __launch_bounds__(256) void gemm_mfma_big(
    const u16* __restrict__ A0, const u16* __restrict__ A1,
    const u16* __restrict__ Wt, const float* __restrict__ bias,
    u16* __restrict__ OutP, int M) {
    int tid = threadIdx.x;
    int lane = tid & 63;
    int w = tid >> 6;  // col-group: cols w*64 .. w*64+63
    int l15 = lane & 15, l4 = lane >> 4;
    int rb0 = blockIdx.x * 16;
    int arow = rb0 + l15;

    const u16* a0base = A0 + (size_t)arow * 512 + l4 * 8;
    const u16* a1base = A1 + (size_t)arow * 1024 + l4 * 8;
    const u16* wbase = Wt + (size_t)(w * 64 + l15) * 1536 + l4 * 8;

    f32x4 acc[4] = {};

    // phase 0: k-chunks over A0 (8 chunks, compile-time offsets)
#pragma unroll
    for (int c = 0; c < 8; ++c) {
        int kk = c * 32;
        bf16x8 ah = *(const bf16x8*)(a0base + kk);
        bf16x8 al = *(const bf16x8*)(a0base + 256 + kk);
        bf16x8 bh[4];
#pragma unroll
        for (int ct = 0; ct < 4; ++ct)
            bh[ct] = *(const bf16x8*)(wbase + ct * 24576 + kk);
#pragma unroll
        for (int ct = 0; ct < 4; ++ct) {
            acc[ct] = MFMA16(ah, bh[ct], acc[ct], 0, 0, 0);
            acc[ct] = MFMA16(al, bh[ct], acc[ct], 0, 0, 0);
        }
    }
    // phase 1: k-chunks over A1 (16 chunks)
#pragma unroll
    for (int c = 0; c < 16; ++c) {
        int kk = c * 32;
        bf16x8 ah = *(const bf16x8*)(a1base + kk);
        bf16x8 al = *(const bf16x8*)(a1base + 512 + kk);
        bf16x8 bh[4];
#pragma unroll
        for (int ct = 0; ct < 4; ++ct)
            bh[ct] = *(const bf16x8*)(wbase + ct * 24576 + 256 + kk);
#pragma unroll
        for (int ct = 0; ct < 4; ++ct) {
            acc[ct] = MFMA16(ah, bh[ct], acc[ct], 0, 0, 0);
            acc[ct] = MFMA16(al, bh[ct], acc[ct], 0, 0, 0);
        }
    }

    // epilogue: bias + relu + split-pack to two planes
#pragma unroll
    for (int ct = 0; ct < 4; ++ct) {
        int col = w * 64 + ct * 16 + l15;
        float b = bias[col];
#pragma unroll
        for (int j = 0; j < 4; ++j) {
            int row = rb0 + l4 * 4 + j;
            if (row < M) {
                float v = fmaxf(acc[ct][j] + b, 0.f);
                u32 pk = pack_split(v);
                OutP[(size_t)row * 512 + col] = (u16)(pk >> 16);
                OutP[(size_t)row * 512 + 256 + col] = (u16)(pk & 0xFFFFu);
            }
        }
    }
}

// ---------------------------------------------------------------------------
// MFMA GEMM (layer 3) + fused log_softmax. Wave = 16 rows, 4 waves/block.
// Full 3-product split (48 cols only; Wt3 L2-resident).
// ---------------------------------------------------------------------------
__global__ __launch_bounds__(256) void gemm_mfma_small(
    const u16* __restrict__ A0, const u16* __restrict__ A1,
    const u16* __restrict__ Wt, const float* __restrict__ bias,
    float* __restrict__ Out, int M) {
    int tid = threadIdx.x;
    int lane = tid & 63;
    int w = tid >> 6;
    int l15 = lane & 15, l4 = lane >> 4;
    int row0 = blockIdx.x * 64 + w * 16;
    int arow = row0 + l15;

    const u16* a0base = A0 + (size_t)arow * 512 + l4 * 8;
    const u16* a1base = A1 + (size_t)arow * 1024 + l4 * 8;
    const u16* wbase = Wt + (size_t)l15 * 1536 + l4 * 8;

    f32x4 acc[3] = {};

#pragma unroll
    for (int c = 0; c < 8; ++c) {
        int kk = c * 32;
        bf16x8 ah = *(const bf16x8*)(a0base + kk);
        bf16x8 al = *(const bf16x8*)(a0base + 256 + kk);
#pragma unroll
        for (int ct = 0; ct < 3; ++ct) {
            const u16* wb = wbase + ct * 24576 + kk;
            bf16x8 bh = *(const bf16x8*)wb;
            bf16x8 bl = *(const bf16x8*)(wb + 768);
            acc[ct] = MFMA16(ah, bh, acc[ct], 0, 0, 0);
            acc[ct] = MFMA16(ah, bl, acc[ct], 0, 0, 0);
            acc[ct] = MFMA16(al, bh, acc[ct], 0, 0, 0);
        }
    }
#pragma unroll
    for (int c = 0; c < 16; ++c) {
        int kk = c * 32;
        bf16x8 ah = *(const bf16x8*)(a1base + kk);
        bf16x8 al = *(const bf16x8*)(a1base + 512 + kk);
#pragma unroll
        for (int ct = 0; ct < 3; ++ct) {
            const u16* wb = wbase + ct * 24576 + 256 + kk;
            bf16x8 bh = *(const bf16x8*)wb;
            bf16x8 bl = *(const bf16x8*)(wb + 768);
            acc[ct] = MFMA16(ah, bh, acc[ct], 0, 0, 0);
            acc[ct] = MFMA16(ah, bl, acc[ct], 0, 0, 0);
            acc[ct] = MFMA16(al, bh, acc[ct], 0, 0, 0);
        }
    }

    bool val2 = (l15 < 8);
    float bq0 = bias[l15];
    float bq1 = bias[16 + l15];
    float bq2 = val2 ? bias[32 + l15] : 0.f;

#pragma unroll
    for (int j = 0; j < 4; ++j) {
        float v0 = acc[0][j] + bq0;
        float v1 = acc[1][j] + bq1;
        float v2 = val2 ? (acc[2][j] + bq2) : -INFINITY;
        float m = fmaxf(fmaxf(v0, v1), v2);
#pragma unroll
        for (int d = 1; d < 16; d <<= 1) m = fmaxf(m, __shfl_xor(m, d, 64));
        float s = expf(v0 - m) + expf(v1 - m) + (val2 ? expf(v2 - m) : 0.f);
#pragma unroll
        for (int d = 1; d < 16; d <<= 1) s += __shfl_xor(s, d, 64);
        float ls = m + logf(s);
        int row = row0 + l4 * 4 + j;
        if (row < M) {
            Out[(size_t)row * C_OUT + l15] = v0 - ls;
            Out[(size_t)row * C_OUT + 16 + l15] = v1 - ls;
            if (val2) Out[(size_t)row * C_OUT + 32 + l15] = v2 - ls;
        }
    }
}

// ---------------------------------------------------------------------------
extern "C" void kernel_launch(void* const* d_in, const int* in_sizes, int n_in,
                              void* d_out, int out_size, void* d_ws, size_t ws_size,
                              hipStream_t stream) {
    const float* x = (const float*)d_in[0];
    const int* ei = (const int*)d_in[1];
    const int* et = (const int*)d_in[2];
    const float* basis1 = (const float*)d_in[3];
    const float* comp1 = (const float*)d_in[4];
    const float* root1 = (const float*)d_in[5];
    const float* bias1 = (const float*)d_in[6];
    const float* basis2 = (const float*)d_in[7];
    const float* comp2 = (const float*)d_in[8];
    const float* root2 = (const float*)d_in[9];
    const float* bias2 = (const float*)d_in[10];
    const float* basis3 = (const float*)d_in[11];
    const float* comp3 = (const float*)d_in[12];
    const float* root3 = (const float*)d_in[13];
    const float* bias3 = (const float*)d_in[14];

    int N_ = in_sizes[0] / 256;
    int E_ = in_sizes[2];
    int M2 = 2 * N_;
    int Mpad = (N_ + 63) & ~63;

    char* p = (char*)d_ws;
    size_t o = 0;
    auto alloc = [&](size_t bytes) {
        void* r = p + o;
        o += (bytes + 255) & ~(size_t)255;
        return r;
    };
    int* cnt = (int*)alloc((size_t)M2 * 4);
    int* elist = (int*)alloc((size_t)M2 * CAP * 4);
    u16* Wt1 = (u16*)alloc((size_t)256 * 1536 * 2);
    u16* Wt2 = (u16*)alloc((size_t)256 * 1536 * 2);
    u16* Wt3 = (u16*)alloc((size_t)48 * 1536 * 2);
    u16* xP = (u16*)alloc((size_t)Mpad * 512 * 2);
    u16* h1P = (u16*)alloc((size_t)Mpad * 512 * 2);
    u16* aggP = (u16*)alloc((size_t)Mpad * 1024 * 2);
    u16* h2P = xP;  // x dead after layer 1
    (void)ws_size;

    // CSR
    zero_i32<<<(M2 + 255) / 256, 256, 0, stream>>>(cnt, M2);
    fill_edges_cap<<<(E_ + 255) / 256, 256, 0, stream>>>(ei, et, cnt, elist, E_);

    // weights (all 3 layers, one dispatch)
    {
        dim3 g(192, 3);
        build_wt_all<<<g, 256, 0, stream>>>(basis1, comp1, root1, Wt1,
                                            basis2, comp2, root2, Wt2,
                                            basis3, comp3, root3, Wt3);
    }

    convert_x<<<(N_ * 128 + 255) / 256, 256, 0, stream>>>(x, xP, N_ * 128);

    int gblocks = (N_ + 15) / 16;    // 16 rows/block (4 waves x 64 cols)
    int sblocks = (N_ + 63) / 64;    // 64 rows/block (4 waves x 16 rows)
    int ablocks = (M2 + 3) / 4;

    // layer 1
    agg_wave<<<ablocks, 256, 0, stream>>>(xP, cnt, elist, aggP, M2);
    gemm_mfma_big<<<gblocks, 256, 0, stream>>>(xP, aggP, Wt1, bias1, h1P, N_);
    // layer 2
    agg_wave<<<ablocks, 256, 0, stream>>>(h1P, cnt, elist, aggP, M2);
    gemm_mfma_big<<<gblocks, 256, 0, stream>>>(h1P, aggP, Wt2, bias2, h2P, N_);
    // layer 3 (+ fused log_softmax)
    agg_wave<<<ablocks, 256, 0, stream>>>(h2P, cnt, elist, aggP, M2);
    gemm_mfma_small<<<sblocks, 256, 0, stream>>>(h2P, aggP, Wt3, bias3, (float*)d_out, N_);
}

// Round 6
// 153.026 us; speedup vs baseline: 2.2549x; 1.5412x over previous
//
#include <hip/hip_runtime.h>
#include <math.h>

#define NREL 2
#define NB 10
#define C_OUT 40
#define CAP 64  // per-(node,rel) capacity; degrees ~Poisson(16), P(>64)~1e-19

typedef unsigned int u32;
typedef unsigned short u16;
typedef __attribute__((ext_vector_type(8))) short bf16x8;
typedef __attribute__((ext_vector_type(4))) float f32x4;

#define MFMA16 __builtin_amdgcn_mfma_f32_16x16x32_bf16

// split-bf16: v ~= bf16(v) + bf16(v - bf16(v)); returns (hi16<<16)|lo16
__device__ __forceinline__ u32 pack_split(float v) {
    u32 u = __float_as_uint(v);
    u32 hi = (u + 0x7FFFu + ((u >> 16) & 1u)) & 0xFFFF0000u;  // RNE to bf16
    float r = v - __uint_as_float(hi);
    u32 ur = __float_as_uint(r);
    u32 lo = ((ur + 0x7FFFu + ((ur >> 16) & 1u)) >> 16) & 0xFFFFu;
    return hi | lo;
}
__device__ __forceinline__ float bfbits(u32 w) { return __uint_as_float(w); }

// ---------------------------------------------------------------------------
// fused: zero cnt + x -> two-plane rows [hi256|lo256]
// ---------------------------------------------------------------------------
__global__ void fused_pre(const float* __restrict__ x, u16* __restrict__ xP,
                          int* __restrict__ cnt, int M2, int n2) {
    int g = blockIdx.x * 256 + threadIdx.x;
    if (g < M2) cnt[g] = 0;
    if (g >= n2) return;
    int i = g * 2;
    int row = i >> 8, f = i & 255;
    u32 p0 = pack_split(x[i]);
    u32 p1 = pack_split(x[i + 1]);
    *(u32*)&xP[(size_t)row * 512 + f] = (p0 >> 16) | (p1 & 0xFFFF0000u);
    *(u32*)&xP[(size_t)row * 512 + 256 + f] = (p0 & 0xFFFFu) | (p1 << 16);
}

__global__ void fill_edges_cap(const int* __restrict__ ei, const int* __restrict__ et,
                               int* __restrict__ cnt, int* __restrict__ elist, int E_) {
    int e = blockIdx.x * 256 + threadIdx.x;
    if (e < E_) {
        int src = ei[e];
        int dst = ei[E_ + e];
        int r = et[e];
        int idx = dst * 2 + r;
        int pos = atomicAdd(&cnt[idx], 1);
        if (pos < CAP) elist[idx * CAP + pos] = src;
    }
}

// ---------------------------------------------------------------------------
// Weight build -> FRAGMENT-MAJOR: Wf[hi: (cb*24+kc)*512 + lane*8 + e][lo: +WHS]
// lane = kg*16 + (c&15); k = kc*32 + kg*8 + e. Coalesced basis reads over c.
// ---------------------------------------------------------------------------
__global__ void build_wt_all(const float* __restrict__ basis1, const float* __restrict__ comp1,
                             const float* __restrict__ root1, u16* __restrict__ Wt1,
                             const float* __restrict__ basis2, const float* __restrict__ comp2,
                             const float* __restrict__ root2, u16* __restrict__ Wt2,
                             const float* __restrict__ basis3, const float* __restrict__ comp3,
                             const float* __restrict__ root3, u16* __restrict__ Wt3) {
    int layer = blockIdx.y;
    const float* basis = (layer == 0) ? basis1 : (layer == 1) ? basis2 : basis3;
    const float* comp = (layer == 0) ? comp1 : (layer == 1) ? comp2 : comp3;
    const float* root = (layer == 0) ? root1 : (layer == 1) ? root2 : root3;
    u16* Wt = (layer == 0) ? Wt1 : (layer == 1) ? Wt2 : Wt3;
    int dreal = (layer == 2) ? C_OUT : 256;
    int dpad = (layer == 2) ? 64 : 256;

    int c = threadIdx.x;
    if (c >= dpad) return;
    size_t WHS = (size_t)(dpad >> 4) * 24 * 512;
    int k0 = blockIdx.x * 4;
    float cw[NREL][NB];
#pragma unroll
    for (int r = 0; r < NREL; ++r)
#pragma unroll
        for (int b = 0; b < NB; ++b) cw[r][b] = comp[r * NB + b];
#pragma unroll
    for (int t = 0; t < 4; ++t) {
        int k = k0 + t;
        float v = 0.f;
        if (c < dreal) {
            if (k < 256) {
                v = root[k * dreal + c];
            } else {
                int r = (k - 256) >> 8;
                int i = (k - 256) & 255;
#pragma unroll
                for (int b = 0; b < NB; ++b)
                    v += cw[r][b] * basis[(b * 256 + i) * dreal + c];
            }
        }
        u32 pk = pack_split(v);
        int cb = c >> 4, kc = k >> 5, kg = (k >> 3) & 3, e = k & 7;
        size_t idx = ((size_t)(cb * 24 + kc) * 64 + (kg * 16 + (c & 15))) * 8 + e;
        Wt[idx] = (u16)(pk >> 16);
        Wt[WHS + idx] = (u16)(pk & 0xFFFFu);
    }
}

// ---------------------------------------------------------------------------
// Aggregation: one WAVE per (node,rel); edge indices loaded once (one/lane),
// broadcast via shfl; 4-deep gather MLP over HI plane; split-packed mean out.
// ---------------------------------------------------------------------------
__global__ __launch_bounds__(256) void agg_wave(const u16* __restrict__ hP,
                                                const int* __restrict__ cnt,
                                                const int* __restrict__ elist,
                                                u16* __restrict__ aggP, int M2) {
    int wid = blockIdx.x * 4 + (threadIdx.x >> 6);
    if (wid >= M2) return;
    int lane = threadIdx.x & 63;
    int c = cnt[wid];
    int cc = min(c, CAP);
    const int* ep = elist + (size_t)wid * CAP;
    int myidx = (lane < cc) ? ep[lane] : 0;
    int fo = lane << 2;

    float s0 = 0.f, s1 = 0.f, s2 = 0.f, s3 = 0.f;
    int j = 0;
    for (; j + 3 < cc; j += 4) {
        int e0 = __shfl(myidx, j, 64);
        int e1 = __shfl(myidx, j + 1, 64);
        int e2 = __shfl(myidx, j + 2, 64);
        int e3 = __shfl(myidx, j + 3, 64);
        uint2 h0 = *(const uint2*)(hP + (size_t)e0 * 512 + fo);
        uint2 h1 = *(const uint2*)(hP + (size_t)e1 * 512 + fo);
        uint2 h2 = *(const uint2*)(hP + (size_t)e2 * 512 + fo);
        uint2 h3 = *(const uint2*)(hP + (size_t)e3 * 512 + fo);
        s0 += bfbits(h0.x << 16) + bfbits(h1.x << 16) + bfbits(h2.x << 16) + bfbits(h3.x << 16);
        s1 += bfbits(h0.x & 0xFFFF0000u) + bfbits(h1.x & 0xFFFF0000u) +
              bfbits(h2.x & 0xFFFF0000u) + bfbits(h3.x & 0xFFFF0000u);
        s2 += bfbits(h0.y << 16) + bfbits(h1.y << 16) + bfbits(h2.y << 16) + bfbits(h3.y << 16);
        s3 += bfbits(h0.y & 0xFFFF0000u) + bfbits(h1.y & 0xFFFF0000u) +
              bfbits(h2.y & 0xFFFF0000u) + bfbits(h3.y & 0xFFFF0000u);
    }
    for (; j < cc; ++j) {
        int e0 = __shfl(myidx, j, 64);
        uint2 h0 = *(const uint2*)(hP + (size_t)e0 * 512 + fo);
        s0 += bfbits(h0.x << 16);
        s1 += bfbits(h0.x & 0xFFFF0000u);
        s2 += bfbits(h0.y << 16);
        s3 += bfbits(h0.y & 0xFFFF0000u);
    }

    float inv = (c > 0) ? 1.f / (float)c : 0.f;
    u32 p0 = pack_split(s0 * inv);
    u32 p1 = pack_split(s1 * inv);
    u32 p2 = pack_split(s2 * inv);
    u32 p3 = pack_split(s3 * inv);

    int n = wid >> 1, r = wid & 1;
    u16* orow = aggP + (size_t)n * 1024 + r * 256 + fo;
    uint2 hw, lw;
    hw.x = (p0 >> 16) | (p1 & 0xFFFF0000u);
    hw.y = (p2 >> 16) | (p3 & 0xFFFF0000u);
    lw.x = (p0 & 0xFFFFu) | (p1 << 16);
    lw.y = (p2 & 0xFFFFu) | (p3 << 16);
    *(uint2*)orow = hw;
    *(uint2*)(orow + 512) = lw;
}

// ---------------------------------------------------------------------------
// MFMA GEMM (layers 1,2): 16-row tile, 4 waves x 64 cols, grid=ceil(M/16).
// A panel (16 x 768 x hi/lo = 48KB) staged in LDS in fragment-major order
// (coalesced global loads, conflict-free ds_read_b128). W fragment-major in
// global (coalesced 1KB/load, L2-resident). Depth-4 register prefetch.
// 2-product split: (ah+al)*bh.
// ---------------------------------------------------------------------------
__global__ __launch_bounds__(256) void gemm_mfma_big(
    const u16* __restrict__ A0, const u16* __restrict__ A1,
    const u16* __restrict__ Wf, const float* __restrict__ bias,
    u16* __restrict__ OutP, int M) {
    __shared__ u16 ldsA[48 * 512];  // [p*24+kc][lane][8]
    int tid = threadIdx.x;
    int lane = tid & 63;
    int w = tid >> 6;
    int l15 = lane & 15, l4 = lane >> 4;
    int rb0 = blockIdx.x * 16;

    // ---- stage: 48 blocks of 1KB; block u=(p*24+kc), lane -> (row=l15,kg=l4)
    {
        uint4 sv[12];
#pragma unroll
        for (int i = 0; i < 12; ++i) {
            int u = i * 4 + w;
            int p = (u >= 24) ? 1 : 0;
            int kc = u - p * 24;
            const u16* src = (kc < 8)
                ? A0 + (size_t)(rb0 + l15) * 512 + p * 256 + kc * 32 + l4 * 8
                : A1 + (size_t)(rb0 + l15) * 1024 + p * 512 + (kc - 8) * 32 + l4 * 8;
            sv[i] = *(const uint4*)src;
        }
#pragma unroll
        for (int i = 0; i < 12; ++i) {
            int u = i * 4 + w;
            *(uint4*)&ldsA[(size_t)u * 512 + lane * 8] = sv[i];
        }
    }
    __syncthreads();

    const u16* wbase = Wf + (size_t)w * 4 * 24 * 512 + lane * 8;  // wave's 4 col-blocks
    f32x4 acc[4] = {};
    bf16x8 pa[4][2], pb[4][4];

    auto LOADC = [&](int c, int s) {
        pa[s][0] = *(const bf16x8*)&ldsA[(size_t)c * 512 + lane * 8];
        pa[s][1] = *(const bf16x8*)&ldsA[(size_t)(24 + c) * 512 + lane * 8];
#pragma unroll
        for (int ct = 0; ct < 4; ++ct)
            pb[s][ct] = *(const bf16x8*)&wbase[(size_t)(ct * 24 + c) * 512];
    };

    LOADC(0, 0);
    LOADC(1, 1);
    LOADC(2, 2);
#pragma unroll
    for (int c = 0; c < 24; ++c) {
        const int s = c & 3;
        if (c + 3 < 24) LOADC(c + 3, (c + 3) & 3);
#pragma unroll
        for (int ct = 0; ct < 4; ++ct) {
            acc[ct] = MFMA16(pa[s][0], pb[s][ct], acc[ct], 0, 0, 0);
            acc[ct] = MFMA16(pa[s][1], pb[s][ct], acc[ct], 0, 0, 0);
        }
    }

    // epilogue: bias + relu + split-pack to two planes
#pragma unroll
    for (int ct = 0; ct < 4; ++ct) {
        int col = w * 64 + ct * 16 + l15;
        float b = bias[col];
#pragma unroll
        for (int j = 0; j < 4; ++j) {
            int row = rb0 + l4 * 4 + j;
            if (row < M) {
                float v = fmaxf(acc[ct][j] + b, 0.f);
                u32 pk = pack_split(v);
                OutP[(size_t)row * 512 + col] = (u16)(pk >> 16);
                OutP[(size_t)row * 512 + 256 + col] = (u16)(pk & 0xFFFFu);
            }
        }
    }
}

// ---------------------------------------------------------------------------
// MFMA GEMM (layer 3) + fused log_softmax: 64-row tile, wave = 16 rows x 48
// cols (3-product). W fragment-major (coalesced); A direct; depth-2 prefetch.
// ---------------------------------------------------------------------------
__global__ __launch_bounds__(256) void gemm_mfma_small(
    const u16* __restrict__ A0, const u16* __restrict__ A1,
    const u16* __restrict__ Wf, const float* __restrict__ bias,
    float* __restrict__ Out, int M) {
    int tid = threadIdx.x;
    int lane = tid & 63;
    int w = tid >> 6;
    int l15 = lane & 15, l4 = lane >> 4;
    int row0 = blockIdx.x * 64 + w * 16;
    int arow = row0 + l15;

    const u16* a0b = A0 + (size_t)arow * 512 + l4 * 8;
    const u16* a1b = A1 + (size_t)arow * 1024 + l4 * 8;
    const u16* wb = Wf + lane * 8;            // hi plane
    const u16* wbl = wb + 4 * 24 * 512;       // lo plane (dpad=64 -> 4 cbs)

    f32x4 acc[3] = {};
    bf16x8 pa[2][2], pbh[2][3], pbl[2][3];

    auto LOADC = [&](int c, int s) {
        if (c < 8) {
            pa[s][0] = *(const bf16x8*)(a0b + c * 32);
            pa[s][1] = *(const bf16x8*)(a0b + 256 + c * 32);
        } else {
            pa[s][0] = *(const bf16x8*)(a1b + (c - 8) * 32);
            pa[s][1] = *(const bf16x8*)(a1b + 512 + (c - 8) * 32);
        }
#pragma unroll
        for (int ct = 0; ct < 3; ++ct) {
            pbh[s][ct] = *(const bf16x8*)(wb + (size_t)(ct * 24 + c) * 512);
            pbl[s][ct] = *(const bf16x8*)(wbl + (size_t)(ct * 24 + c) * 512);
        }
    };

    LOADC(0, 0);
#pragma unroll
    for (int c = 0; c < 24; ++c) {
        const int s = c & 1;
        if (c + 1 < 24) LOADC(c + 1, (c + 1) & 1);
#pragma unroll
        for (int ct = 0; ct < 3; ++ct) {
            acc[ct] = MFMA16(pa[s][0], pbh[s][ct], acc[ct], 0, 0, 0);
            acc[ct] = MFMA16(pa[s][0], pbl[s][ct], acc[ct], 0, 0, 0);
            acc[ct] = MFMA16(pa[s][1], pbh[s][ct], acc[ct], 0, 0, 0);
        }
    }

    bool val2 = (l15 < 8);
    float bq0 = bias[l15];
    float bq1 = bias[16 + l15];
    float bq2 = val2 ? bias[32 + l15] : 0.f;

#pragma unroll
    for (int j = 0; j < 4; ++j) {
        float v0 = acc[0][j] + bq0;
        float v1 = acc[1][j] + bq1;
        float v2 = val2 ? (acc[2][j] + bq2) : -INFINITY;
        float m = fmaxf(fmaxf(v0, v1), v2);
#pragma unroll
        for (int d = 1; d < 16; d <<= 1) m = fmaxf(m, __shfl_xor(m, d, 64));
        float s = expf(v0 - m) + expf(v1 - m) + (val2 ? expf(v2 - m) : 0.f);
#pragma unroll
        for (int d = 1; d < 16; d <<= 1) s += __shfl_xor(s, d, 64);
        float ls = m + logf(s);
        int row = row0 + l4 * 4 + j;
        if (row < M) {
            Out[(size_t)row * C_OUT + l15] = v0 - ls;
            Out[(size_t)row * C_OUT + 16 + l15] = v1 - ls;
            if (val2) Out[(size_t)row * C_OUT + 32 + l15] = v2 - ls;
        }
    }
}

// ---------------------------------------------------------------------------
extern "C" void kernel_launch(void* const* d_in, const int* in_sizes, int n_in,
                              void* d_out, int out_size, void* d_ws, size_t ws_size,
                              hipStream_t stream) {
    const float* x = (const float*)d_in[0];
    const int* ei = (const int*)d_in[1];
    const int* et = (const int*)d_in[2];
    const float* basis1 = (const float*)d_in[3];
    const float* comp1 = (const float*)d_in[4];
    const float* root1 = (const float*)d_in[5];
    const float* bias1 = (const float*)d_in[6];
    const float* basis2 = (const float*)d_in[7];
    const float* comp2 = (const float*)d_in[8];
    const float* root2 = (const float*)d_in[9];
    const float* bias2 = (const float*)d_in[10];
    const float* basis3 = (const float*)d_in[11];
    const float* comp3 = (const float*)d_in[12];
    const float* root3 = (const float*)d_in[13];
    const float* bias3 = (const float*)d_in[14];

    int N_ = in_sizes[0] / 256;
    int E_ = in_sizes[2];
    int M2 = 2 * N_;
    int Mpad = (N_ + 63) & ~63;

    char* p = (char*)d_ws;
    size_t o = 0;
    auto alloc = [&](size_t bytes) {
        void* r = p + o;
        o += (bytes + 255) & ~(size_t)255;
        return r;
    };
    int* cnt = (int*)alloc((size_t)M2 * 4);
    int* elist = (int*)alloc((size_t)M2 * CAP * 4);
    u16* Wf1 = (u16*)alloc((size_t)2 * 16 * 24 * 512 * 2);  // hi+lo planes
    u16* Wf2 = (u16*)alloc((size_t)2 * 16 * 24 * 512 * 2);
    u16* Wf3 = (u16*)alloc((size_t)2 * 4 * 24 * 512 * 2);
    u16* xP = (u16*)alloc((size_t)Mpad * 512 * 2);
    u16* h1P = (u16*)alloc((size_t)Mpad * 512 * 2);
    u16* aggP = (u16*)alloc((size_t)Mpad * 1024 * 2);
    u16* h2P = xP;  // x dead after layer 1
    (void)ws_size;

    int n2 = N_ * 128;

    // zero cnt + convert x (fused)
    fused_pre<<<(n2 + 255) / 256, 256, 0, stream>>>(x, xP, cnt, M2, n2);
    // weights (fragment-major, all 3 layers)
    {
        dim3 g(192, 3);
        build_wt_all<<<g, 256, 0, stream>>>(basis1, comp1, root1, Wf1,
                                            basis2, comp2, root2, Wf2,
                                            basis3, comp3, root3, Wf3);
    }
    // CSR fill
    fill_edges_cap<<<(E_ + 255) / 256, 256, 0, stream>>>(ei, et, cnt, elist, E_);

    int gblocks = (N_ + 15) / 16;
    int sblocks = (N_ + 63) / 64;
    int ablocks = (M2 + 3) / 4;

    // layer 1
    agg_wave<<<ablocks, 256, 0, stream>>>(xP, cnt, elist, aggP, M2);
    gemm_mfma_big<<<gblocks, 256, 0, stream>>>(xP, aggP, Wf1, bias1, h1P, N_);
    // layer 2
    agg_wave<<<ablocks, 256, 0, stream>>>(h1P, cnt, elist, aggP, M2);
    gemm_mfma_big<<<gblocks, 256, 0, stream>>>(h1P, aggP, Wf2, bias2, h2P, N_);
    // layer 3 (+ fused log_softmax)
    agg_wave<<<ablocks, 256, 0, stream>>>(h2P, cnt, elist, aggP, M2);
    gemm_mfma_small<<<sblocks, 256, 0, stream>>>(h2P, aggP, Wf3, bias3, (float*)d_out, N_);
}

// Round 7
// 137.663 us; speedup vs baseline: 2.5066x; 1.1116x over previous
//
#include <hip/hip_runtime.h>
#include <math.h>

#define NREL 2
#define NB 10
#define C_OUT 40
#define CAP 64  // per-(node,rel) capacity; degrees ~Poisson(16), P(>64)~1e-19

typedef unsigned int u32;
typedef unsigned short u16;
typedef __attribute__((ext_vector_type(8))) short bf16x8;
typedef __attribute__((ext_vector_type(4))) float f32x4;

#define MFMA16 __builtin_amdgcn_mfma_f32_16x16x32_bf16

// RNE round fp32 -> bf16 (returns low 16 bits)
__device__ __forceinline__ u32 rne16(float v) {
    u32 u = __float_as_uint(v);
    return (u + 0x7FFFu + ((u >> 16) & 1u)) >> 16;
}
// split-bf16 (for W): (hi16<<16)|lo16
__device__ __forceinline__ u32 pack_split(float v) {
    u32 u = __float_as_uint(v);
    u32 hi = (u + 0x7FFFu + ((u >> 16) & 1u)) & 0xFFFF0000u;
    float r = v - __uint_as_float(hi);
    u32 ur = __float_as_uint(r);
    u32 lo = ((ur + 0x7FFFu + ((ur >> 16) & 1u)) >> 16) & 0xFFFFu;
    return hi | lo;
}
__device__ __forceinline__ float bfbits(u32 w) { return __uint_as_float(w); }

// ---------------------------------------------------------------------------
// fused: zero cnt + x -> bf16 rows [N][256]
// ---------------------------------------------------------------------------
__global__ void fused_pre(const float* __restrict__ x, u16* __restrict__ xP,
                          int* __restrict__ cnt, int M2, int n2) {
    int g = blockIdx.x * 256 + threadIdx.x;
    if (g < M2) cnt[g] = 0;
    if (g >= n2) return;
    int i = g * 2;
    u32 w = rne16(x[i]) | (rne16(x[i + 1]) << 16);
    *(u32*)&xP[i] = w;
}

__global__ void fill_edges_cap(const int* __restrict__ ei, const int* __restrict__ et,
                               int* __restrict__ cnt, int* __restrict__ elist, int E_) {
    int e = blockIdx.x * 256 + threadIdx.x;
    if (e < E_) {
        int src = ei[e];
        int dst = ei[E_ + e];
        int r = et[e];
        int idx = dst * 2 + r;
        int pos = atomicAdd(&cnt[idx], 1);
        if (pos < CAP) elist[idx * CAP + pos] = src;
    }
}

// ---------------------------------------------------------------------------
// Weight build -> FRAGMENT-MAJOR hi plane; lo plane only for layer 3.
// idx = ((cb*24+kc)*64 + kg*16 + (c&15))*8 + e;  k = kc*32+kg*8+e, cb = c>>4
// ---------------------------------------------------------------------------
__global__ void build_wt_all(const float* __restrict__ basis1, const float* __restrict__ comp1,
                             const float* __restrict__ root1, u16* __restrict__ Wt1,
                             const float* __restrict__ basis2, const float* __restrict__ comp2,
                             const float* __restrict__ root2, u16* __restrict__ Wt2,
                             const float* __restrict__ basis3, const float* __restrict__ comp3,
                             const float* __restrict__ root3, u16* __restrict__ Wt3) {
    int layer = blockIdx.y;
    const float* basis = (layer == 0) ? basis1 : (layer == 1) ? basis2 : basis3;
    const float* comp = (layer == 0) ? comp1 : (layer == 1) ? comp2 : comp3;
    const float* root = (layer == 0) ? root1 : (layer == 1) ? root2 : root3;
    u16* Wt = (layer == 0) ? Wt1 : (layer == 1) ? Wt2 : Wt3;
    int dreal = (layer == 2) ? C_OUT : 256;
    int dpad = (layer == 2) ? 64 : 256;

    int c = threadIdx.x;
    if (c >= dpad) return;
    int k0 = blockIdx.x * 4;
    float cw[NREL][NB];
#pragma unroll
    for (int r = 0; r < NREL; ++r)
#pragma unroll
        for (int b = 0; b < NB; ++b) cw[r][b] = comp[r * NB + b];
#pragma unroll
    for (int t = 0; t < 4; ++t) {
        int k = k0 + t;
        float v = 0.f;
        if (c < dreal) {
            if (k < 256) {
                v = root[k * dreal + c];
            } else {
                int r = (k - 256) >> 8;
                int i = (k - 256) & 255;
#pragma unroll
                for (int b = 0; b < NB; ++b)
                    v += cw[r][b] * basis[(b * 256 + i) * dreal + c];
            }
        }
        u32 pk = pack_split(v);
        int cb = c >> 4, kc = k >> 5, kg = (k >> 3) & 3, e = k & 7;
        size_t idx = ((size_t)(cb * 24 + kc) * 64 + (kg * 16 + (c & 15))) * 8 + e;
        Wt[idx] = (u16)(pk >> 16);
        if (layer == 2) Wt[(size_t)4 * 24 * 512 + idx] = (u16)(pk & 0xFFFFu);
    }
}

// ---------------------------------------------------------------------------
// Aggregation: one WAVE per (node,rel). Lane owns 8 features (uint4);
// half-wave 0/1 each take one edge of a pair -> 2 edges per load round,
// 4-pair unroll (8 edges in flight). Final cross-half shfl_xor(32) combine.
// In rows: [N][256] bf16. Out rows: [N][512] bf16 (rel0|rel1).
// ---------------------------------------------------------------------------
__global__ __launch_bounds__(256) void agg_wave(const u16* __restrict__ hP,
                                                const int* __restrict__ cnt,
                                                const int* __restrict__ elist,
                                                u16* __restrict__ aggP, int M2) {
    int wid = blockIdx.x * 4 + (threadIdx.x >> 6);
    if (wid >= M2) return;
    int lane = threadIdx.x & 63;
    int half = lane >> 5;
    int fl = (lane & 31) * 8;  // u16 offset of this lane's 8 features
    int c = cnt[wid];
    int cc = min(c, CAP);
    const int* ep = elist + (size_t)wid * CAP;
    int myidx = (lane < cc) ? ep[lane] : 0;

    float s0 = 0.f, s1 = 0.f, s2 = 0.f, s3 = 0.f, s4 = 0.f, s5 = 0.f, s6 = 0.f, s7 = 0.f;

#define ACC8(q)                                    \
    do {                                           \
        s0 += bfbits((q).x << 16);                 \
        s1 += bfbits((q).x & 0xFFFF0000u);         \
        s2 += bfbits((q).y << 16);                 \
        s3 += bfbits((q).y & 0xFFFF0000u);         \
        s4 += bfbits((q).z << 16);                 \
        s5 += bfbits((q).z & 0xFFFF0000u);         \
        s6 += bfbits((q).w << 16);                 \
        s7 += bfbits((q).w & 0xFFFF0000u);         \
    } while (0)

    int fullpairs = cc >> 1;
    int jp = 0;
    for (; jp + 3 < fullpairs; jp += 4) {
        int e0 = __shfl(myidx, 2 * jp + half, 64);
        int e1 = __shfl(myidx, 2 * jp + 2 + half, 64);
        int e2 = __shfl(myidx, 2 * jp + 4 + half, 64);
        int e3 = __shfl(myidx, 2 * jp + 6 + half, 64);
        uint4 q0 = *(const uint4*)(hP + (size_t)e0 * 256 + fl);
        uint4 q1 = *(const uint4*)(hP + (size_t)e1 * 256 + fl);
        uint4 q2 = *(const uint4*)(hP + (size_t)e2 * 256 + fl);
        uint4 q3 = *(const uint4*)(hP + (size_t)e3 * 256 + fl);
        ACC8(q0);
        ACC8(q1);
        ACC8(q2);
        ACC8(q3);
    }
    for (; jp < fullpairs; ++jp) {
        int e0 = __shfl(myidx, 2 * jp + half, 64);
        uint4 q0 = *(const uint4*)(hP + (size_t)e0 * 256 + fl);
        ACC8(q0);
    }
    if (cc & 1) {
        int e0 = __shfl(myidx, cc - 1, 64);
        if (half == 0) {
            uint4 q0 = *(const uint4*)(hP + (size_t)e0 * 256 + fl);
            ACC8(q0);
        }
    }
#undef ACC8

    // combine the two half-wave partial sums (same features, disjoint edges)
    s0 += __shfl_xor(s0, 32, 64);
    s1 += __shfl_xor(s1, 32, 64);
    s2 += __shfl_xor(s2, 32, 64);
    s3 += __shfl_xor(s3, 32, 64);
    s4 += __shfl_xor(s4, 32, 64);
    s5 += __shfl_xor(s5, 32, 64);
    s6 += __shfl_xor(s6, 32, 64);
    s7 += __shfl_xor(s7, 32, 64);

    if (half == 0) {
        float inv = (c > 0) ? 1.f / (float)c : 0.f;
        uint4 o;
        o.x = rne16(s0 * inv) | (rne16(s1 * inv) << 16);
        o.y = rne16(s2 * inv) | (rne16(s3 * inv) << 16);
        o.z = rne16(s4 * inv) | (rne16(s5 * inv) << 16);
        o.w = rne16(s6 * inv) | (rne16(s7 * inv) << 16);
        int n = wid >> 1, r = wid & 1;
        *(uint4*)&aggP[(size_t)n * 512 + r * 256 + fl] = o;
    }
}

// ---------------------------------------------------------------------------
// MFMA GEMM (layers 1,2), 1-product bf16: Out[M][256] = relu([A0|A1] @ Whi + b)
// Block: 512 thr = 8 waves (2 row-halves x 4 col-blocks); 32-row LDS panel
// (fragment-major, 48KB); W fragment-major from global (coalesced, L2-hot);
// depth-4 register prefetch rotation. Grid = ceil(M/32) -> 2504 waves.
// ---------------------------------------------------------------------------
__global__ __launch_bounds__(512) void gemm_mfma_big(
    const u16* __restrict__ A0, const u16* __restrict__ A1,
    const u16* __restrict__ Wf, const float* __restrict__ bias,
    u16* __restrict__ OutP, int M) {
    __shared__ u16 ldsA[48 * 512];  // [r16*24+kc][lane][8]
    int tid = threadIdx.x;
    int lane = tid & 63;
    int w = tid >> 6;
    int wr = w >> 2, wc = w & 3;
    int l15 = lane & 15, l4 = lane >> 4;
    int rb0 = blockIdx.x * 32;

    // stage 32x768 bf16 panel, fragment-major: unit u = r16*24+kc (1KB each)
    {
        uint4 sv[6];
#pragma unroll
        for (int i = 0; i < 6; ++i) {
            int u = i * 8 + w;
            int r16 = (u >= 24) ? 1 : 0;
            int kc = u - r16 * 24;
            int row = rb0 + r16 * 16 + l15;
            const u16* src = (kc < 8) ? A0 + (size_t)row * 256 + kc * 32 + l4 * 8
                                      : A1 + (size_t)row * 512 + (kc - 8) * 32 + l4 * 8;
            sv[i] = *(const uint4*)src;
        }
#pragma unroll
        for (int i = 0; i < 6; ++i) {
            int u = i * 8 + w;
            *(uint4*)&ldsA[(size_t)u * 512 + lane * 8] = sv[i];
        }
    }
    __syncthreads();

    const u16* wbase = Wf + (size_t)wc * 4 * 24 * 512 + lane * 8;
    const u16* abase = ldsA + (size_t)wr * 24 * 512 + lane * 8;
    f32x4 acc[4] = {};
    bf16x8 pa[4], pb[4][4];

    auto LOADC = [&](int c, int s) {
        pa[s] = *(const bf16x8*)&abase[(size_t)c * 512];
#pragma unroll
        for (int ct = 0; ct < 4; ++ct)
            pb[s][ct] = *(const bf16x8*)&wbase[(size_t)(ct * 24 + c) * 512];
    };

    LOADC(0, 0);
    LOADC(1, 1);
    LOADC(2, 2);
#pragma unroll
    for (int c = 0; c < 24; ++c) {
        const int s = c & 3;
        if (c + 3 < 24) LOADC(c + 3, (c + 3) & 3);
#pragma unroll
        for (int ct = 0; ct < 4; ++ct)
            acc[ct] = MFMA16(pa[s], pb[s][ct], acc[ct], 0, 0, 0);
    }

    // epilogue: bias + relu + bf16 store
#pragma unroll
    for (int ct = 0; ct < 4; ++ct) {
        int col = wc * 64 + ct * 16 + l15;
        float b = bias[col];
#pragma unroll
        for (int j = 0; j < 4; ++j) {
            int row = rb0 + wr * 16 + l4 * 4 + j;
            if (row < M) {
                float v = fmaxf(acc[ct][j] + b, 0.f);
                OutP[(size_t)row * 256 + col] = (u16)rne16(v);
            }
        }
    }
}

// ---------------------------------------------------------------------------
// MFMA GEMM (layer 3) + fused log_softmax: A bf16, W split (2-product).
// 64-row blocks, wave = 16 rows x 48 cols; depth-2 prefetch.
// ---------------------------------------------------------------------------
__global__ __launch_bounds__(256) void gemm_mfma_small(
    const u16* __restrict__ A0, const u16* __restrict__ A1,
    const u16* __restrict__ Wf, const float* __restrict__ bias,
    float* __restrict__ Out, int M) {
    int tid = threadIdx.x;
    int lane = tid & 63;
    int w = tid >> 6;
    int l15 = lane & 15, l4 = lane >> 4;
    int row0 = blockIdx.x * 64 + w * 16;
    int arow = row0 + l15;

    const u16* a0b = A0 + (size_t)arow * 256 + l4 * 8;
    const u16* a1b = A1 + (size_t)arow * 512 + l4 * 8;
    const u16* wb = Wf + lane * 8;            // hi plane
    const u16* wbl = wb + 4 * 24 * 512;       // lo plane

    f32x4 acc[3] = {};
    bf16x8 pa[2], pbh[2][3], pbl[2][3];

    auto LOADC = [&](int c, int s) {
        pa[s] = (c < 8) ? *(const bf16x8*)(a0b + c * 32)
                        : *(const bf16x8*)(a1b + (c - 8) * 32);
#pragma unroll
        for (int ct = 0; ct < 3; ++ct) {
            pbh[s][ct] = *(const bf16x8*)(wb + (size_t)(ct * 24 + c) * 512);
            pbl[s][ct] = *(const bf16x8*)(wbl + (size_t)(ct * 24 + c) * 512);
        }
    };

    LOADC(0, 0);
#pragma unroll
    for (int c = 0; c < 24; ++c) {
        const int s = c & 1;
        if (c + 1 < 24) LOADC(c + 1, (c + 1) & 1);
#pragma unroll
        for (int ct = 0; ct < 3; ++ct) {
            acc[ct] = MFMA16(pa[s], pbh[s][ct], acc[ct], 0, 0, 0);
            acc[ct] = MFMA16(pa[s], pbl[s][ct], acc[ct], 0, 0, 0);
        }
    }

    bool val2 = (l15 < 8);
    float bq0 = bias[l15];
    float bq1 = bias[16 + l15];
    float bq2 = val2 ? bias[32 + l15] : 0.f;

#pragma unroll
    for (int j = 0; j < 4; ++j) {
        float v0 = acc[0][j] + bq0;
        float v1 = acc[1][j] + bq1;
        float v2 = val2 ? (acc[2][j] + bq2) : -INFINITY;
        float m = fmaxf(fmaxf(v0, v1), v2);
#pragma unroll
        for (int d = 1; d < 16; d <<= 1) m = fmaxf(m, __shfl_xor(m, d, 64));
        float s = expf(v0 - m) + expf(v1 - m) + (val2 ? expf(v2 - m) : 0.f);
#pragma unroll
        for (int d = 1; d < 16; d <<= 1) s += __shfl_xor(s, d, 64);
        float ls = m + logf(s);
        int row = row0 + l4 * 4 + j;
        if (row < M) {
            Out[(size_t)row * C_OUT + l15] = v0 - ls;
            Out[(size_t)row * C_OUT + 16 + l15] = v1 - ls;
            if (val2) Out[(size_t)row * C_OUT + 32 + l15] = v2 - ls;
        }
    }
}

// ---------------------------------------------------------------------------
extern "C" void kernel_launch(void* const* d_in, const int* in_sizes, int n_in,
                              void* d_out, int out_size, void* d_ws, size_t ws_size,
                              hipStream_t stream) {
    const float* x = (const float*)d_in[0];
    const int* ei = (const int*)d_in[1];
    const int* et = (const int*)d_in[2];
    const float* basis1 = (const float*)d_in[3];
    const float* comp1 = (const float*)d_in[4];
    const float* root1 = (const float*)d_in[5];
    const float* bias1 = (const float*)d_in[6];
    const float* basis2 = (const float*)d_in[7];
    const float* comp2 = (const float*)d_in[8];
    const float* root2 = (const float*)d_in[9];
    const float* bias2 = (const float*)d_in[10];
    const float* basis3 = (const float*)d_in[11];
    const float* comp3 = (const float*)d_in[12];
    const float* root3 = (const float*)d_in[13];
    const float* bias3 = (const float*)d_in[14];

    int N_ = in_sizes[0] / 256;
    int E_ = in_sizes[2];
    int M2 = 2 * N_;
    int Mpad = (N_ + 63) & ~63;

    char* p = (char*)d_ws;
    size_t o = 0;
    auto alloc = [&](size_t bytes) {
        void* r = p + o;
        o += (bytes + 255) & ~(size_t)255;
        return r;
    };
    int* cnt = (int*)alloc((size_t)M2 * 4);
    int* elist = (int*)alloc((size_t)M2 * CAP * 4);
    u16* Wf1 = (u16*)alloc((size_t)16 * 24 * 512 * 2);       // hi only
    u16* Wf2 = (u16*)alloc((size_t)16 * 24 * 512 * 2);       // hi only
    u16* Wf3 = (u16*)alloc((size_t)2 * 4 * 24 * 512 * 2);    // hi + lo
    u16* xP = (u16*)alloc((size_t)Mpad * 256 * 2);
    u16* h1P = (u16*)alloc((size_t)Mpad * 256 * 2);
    u16* aggP = (u16*)alloc((size_t)Mpad * 512 * 2);
    u16* h2P = xP;  // x dead after layer 1
    (void)ws_size;

    int n2 = N_ * 128;

    fused_pre<<<(n2 + 255) / 256, 256, 0, stream>>>(x, xP, cnt, M2, n2);
    {
        dim3 g(192, 3);
        build_wt_all<<<g, 256, 0, stream>>>(basis1, comp1, root1, Wf1,
                                            basis2, comp2, root2, Wf2,
                                            basis3, comp3, root3, Wf3);
    }
    fill_edges_cap<<<(E_ + 255) / 256, 256, 0, stream>>>(ei, et, cnt, elist, E_);

    int gblocks = (N_ + 31) / 32;
    int sblocks = (N_ + 63) / 64;
    int ablocks = (M2 + 3) / 4;

    // layer 1
    agg_wave<<<ablocks, 256, 0, stream>>>(xP, cnt, elist, aggP, M2);
    gemm_mfma_big<<<gblocks, 512, 0, stream>>>(xP, aggP, Wf1, bias1, h1P, N_);
    // layer 2
    agg_wave<<<ablocks, 256, 0, stream>>>(h1P, cnt, elist, aggP, M2);
    gemm_mfma_big<<<gblocks, 512, 0, stream>>>(h1P, aggP, Wf2, bias2, h2P, N_);
    // layer 3 (+ fused log_softmax)
    agg_wave<<<ablocks, 256, 0, stream>>>(h2P, cnt, elist, aggP, M2);
    gemm_mfma_small<<<sblocks, 256, 0, stream>>>(h2P, aggP, Wf3, bias3, (float*)d_out, N_);
}